// Round 5
// baseline (425.075 us; speedup 1.0000x reference)
//
#include <hip/hip_runtime.h>
#include <math.h>

#define H_DIM 2880
#define E_NUM 32
#define TOPK 4
#define NCH 12           // h-chunks; HCHUNK = 960 B -> 15 aligned 64-B lines/token
#define HCHUNK 240
#define TT 128           // tokens per block
#define KS 12            // LDS row stride 12 dw: measured 0-conflict class (R3)
#define NS 20            // HCHUNK / KS

typedef float vf16 __attribute__((ext_vector_type(16)));

// async global->LDS DMA, 16B/lane; LDS dest = wave-uniform base + lane*16.
#define GLD16(gp, lp)                                                  \
    __builtin_amdgcn_global_load_lds(                                  \
        (const __attribute__((address_space(1))) void*)(gp),           \
        (__attribute__((address_space(3))) void*)(lp), 16, 0, 0)

// ---------------- Kernel A: transpose weight [E][H] -> wt[H][E] ----------------
__global__ void transpose_w(const float* __restrict__ w, float* __restrict__ wt) {
    __shared__ float tile[32][33];
    const int h0 = blockIdx.x * 32;
    const int tx = threadIdx.x;
    const int ty = threadIdx.y;
    tile[tx][ty] = w[ty * H_DIM + h0 + tx];
    __syncthreads();
    wt[(h0 + ty) * E_NUM + tx] = tile[ty][tx];
}

// ---------------- Kernel B: partial logits per h-chunk ----------------
// grid (T/TT, NCH) = 1536 blocks; __launch_bounds__(256,4) -> 4 blocks/CU
// (16 waves/CU). Block = 128 tokens x 2 expert-halves; thread = 1 token x 16
// experts (acc[16]). DMA is issued at the TOP of each stage into buf[s&1] and
// drained by the immediately-following barrier: both RAW and WAR on each LDS
// buffer are separated from any concurrent access by >= one barrier in every
// legal instruction schedule (R4's issue-below-barrier shape was not).
__global__ __launch_bounds__(256, 4) void partial_logits(
    const float* __restrict__ x, const float* __restrict__ wt,
    float* __restrict__ part, int T) {
    __shared__ float xs[2][TT * KS];  // 2 x 6 KB
    const int tid = threadIdx.x;
    const int t0 = blockIdx.x * TT;
    const int k0 = blockIdx.y * HCHUNK;
    const int wave = tid >> 6, lane = tid & 63;
    const int half = tid >> 7;       // expert half (wave-uniform)
    const int tok = tid & 127;       // token within block

    // stage = TT*KS = 1536 floats = 384 float4 slots; waves 0..2 issue 2 DMA.
    const bool dma = (wave < 3);
    const float* g[2];
    int lo[2];
    if (dma) {
#pragma unroll
        for (int i = 0; i < 2; ++i) {
            int f = wave * 128 + i * 64 + lane;  // slot: lane-contiguous per instr
            int r = f / 3, c = f % 3;            // token row, float4-col in 12-dw run
            g[i] = x + (size_t)(t0 + r) * H_DIM + k0 + c * 4;
            lo[i] = f * 4;
        }
    }

    float acc[16];
#pragma unroll
    for (int e = 0; e < 16; ++e) acc[e] = 0.f;

    for (int s = 0; s < NS; ++s) {
        if (dma) {  // issue stage s's DMA, then drain at the barrier below
#pragma unroll
            for (int i = 0; i < 2; ++i)
                GLD16(g[i] + (size_t)s * KS, &xs[s & 1][lo[i]]);
        }
        __syncthreads();  // vmcnt(0)+lgkmcnt(0) drain + block sync: buf[s&1] ready,
                          // and all reads of buf[s&1] from stage s-2 long finished.
        const float* xrow = &xs[s & 1][tok * KS];
        const int kb = k0 + s * KS;
#pragma unroll
        for (int kk = 0; kk < 3; ++kk) {
            float4 xv = *(const float4*)&xrow[kk * 4];
#pragma unroll
            for (int c = 0; c < 4; ++c) {
                float xk = (&xv.x)[c];
                int kg = kb + kk * 4 + c;  // wave-uniform
                vf16 wv = *(const vf16*)(wt + (size_t)kg * E_NUM + half * 16);
#pragma unroll
                for (int e = 0; e < 16; ++e) acc[e] += xk * wv[e];
            }
        }
    }

    // 64 B contiguous per thread
    float4* o = (float4*)(part + ((size_t)blockIdx.y * T + t0 + tok) * E_NUM + half * 16);
#pragma unroll
    for (int j = 0; j < 4; ++j)
        o[j] = make_float4(acc[j * 4], acc[j * 4 + 1], acc[j * 4 + 2], acc[j * 4 + 3]);
}

// ---------------- Kernel C: reduce 12 chunks + bias, top-4, softmax ----------------
// R3-bench-proven pattern: block 256 = 64 tokens x 4 waves; wave g sums chunks
// 3g..3g+2; waves 1-3 park partials in LDS; wave 0 reduces + top-k + softmax.
__global__ __launch_bounds__(256) void topk_softmax(
    const float* __restrict__ part, const float* __restrict__ bias,
    float* __restrict__ out, int T) {
    __shared__ float red[3][64][36];  // pad 32->36: conflict-safe stride
    const int tid = threadIdx.x, g = tid >> 6, l = tid & 63;
    const int t = blockIdx.x * 64 + l;

    float s[E_NUM];
#pragma unroll
    for (int e = 0; e < E_NUM; ++e) s[e] = 0.f;
#pragma unroll
    for (int q = 0; q < 3; ++q) {
        const int hc = g * 3 + q;
        const float4* p4 = (const float4*)(part + ((size_t)hc * T + t) * E_NUM);
#pragma unroll
        for (int j = 0; j < 8; ++j) {
            float4 p = p4[j];
            s[j * 4] += p.x; s[j * 4 + 1] += p.y;
            s[j * 4 + 2] += p.z; s[j * 4 + 3] += p.w;
        }
    }
    if (g > 0) {
#pragma unroll
        for (int j = 0; j < 8; ++j)
            *(float4*)&red[g - 1][l][j * 4] =
                make_float4(s[j * 4], s[j * 4 + 1], s[j * 4 + 2], s[j * 4 + 3]);
    }
    __syncthreads();
    if (g == 0) {
        float logit[E_NUM];
        const float4* b4 = (const float4*)bias;
#pragma unroll
        for (int j = 0; j < 8; ++j) {
            float4 b = b4[j];
            logit[j * 4] = b.x; logit[j * 4 + 1] = b.y;
            logit[j * 4 + 2] = b.z; logit[j * 4 + 3] = b.w;
        }
#pragma unroll
        for (int e = 0; e < E_NUM; ++e)
            logit[e] += s[e] + red[0][l][e] + red[1][l][e] + red[2][l][e];

        // top-4 descending, ties -> lowest index (strict >, ascending scan)
        int idx[TOPK];
        float val[TOPK];
#pragma unroll
        for (int k = 0; k < TOPK; ++k) {
            float best = -INFINITY;
            int bi = 0;
#pragma unroll
            for (int e = 0; e < E_NUM; ++e) {
                bool taken = false;
                for (int p = 0; p < k; ++p) taken = taken || (idx[p] == e);
                float v = logit[e];
                if (!taken && v > best) { best = v; bi = e; }
            }
            idx[k] = bi;
            val[k] = best;
        }
        float ex[TOPK], sum = 0.f;
#pragma unroll
        for (int k = 0; k < TOPK; ++k) { ex[k] = expf(val[k] - val[0]); sum += ex[k]; }
        float inv = 1.f / sum;
#pragma unroll
        for (int k = 0; k < TOPK; ++k) {
            out[(size_t)t * 4 + k] = (float)idx[k];
            out[(size_t)T * 4 + (size_t)t * 4 + k] = ex[k] * inv;
        }
    }
}

extern "C" void kernel_launch(void* const* d_in, const int* in_sizes, int n_in,
                              void* d_out, int out_size, void* d_ws, size_t ws_size,
                              hipStream_t stream) {
    const float* x    = (const float*)d_in[0];  // [B,S,H] fp32
    const float* w    = (const float*)d_in[1];  // [E,H] fp32
    const float* bias = (const float*)d_in[2];  // [E] fp32
    float* out = (float*)d_out;

    const int T = in_sizes[0] / H_DIM;  // 16384

    float* part = (float*)d_ws;                    // [NCH][T][E] = 25.2 MB
    float* wt = part + (size_t)NCH * T * E_NUM;    // [H][E]

    transpose_w<<<dim3(H_DIM / 32), dim3(32, 32), 0, stream>>>(w, wt);
    partial_logits<<<dim3(T / TT, NCH), 256, 0, stream>>>(x, wt, part, T);
    topk_softmax<<<dim3(T / 64), 256, 0, stream>>>(part, bias, out, T);
}

// Round 6
// 385.998 us; speedup vs baseline: 1.1012x; 1.1012x over previous
//
#include <hip/hip_runtime.h>
#include <math.h>

#define H_DIM 2880
#define E_NUM 32
#define TOPK 4
#define TT 64        // tokens per block (= lanes per wave)
#define SW 144       // h floats per token per stage
#define NSTG 20      // H_DIM / SW
#define LROW 148     // padded LDS row stride in dw (148%32=20 -> ~8-way max alias)
#define SBUF (TT * LROW)  // 9472 dw per buffer

typedef float vf16 __attribute__((ext_vector_type(16)));

// async global->LDS DMA, 16B/lane (active lanes only); LDS dest = uniform base
// + lane*16. One instr = ONE token's contiguous 576-B run (36 active lanes) —
// R2..R5 staged ~21 scattered tokens per instr, this is the coalescing fix.
#define GLD16(gp, lp)                                                  \
    __builtin_amdgcn_global_load_lds(                                  \
        (const __attribute__((address_space(1))) void*)(gp),           \
        (__attribute__((address_space(3))) void*)(lp), 16, 0, 0)

// ---------------- Kernel A: transpose weight [E][H] -> wt[H][E] ----------------
__global__ void transpose_w(const float* __restrict__ w, float* __restrict__ wt) {
    __shared__ float tile[32][33];
    const int h0 = blockIdx.x * 32;
    const int tx = threadIdx.x;
    const int ty = threadIdx.y;
    tile[tx][ty] = w[ty * H_DIM + h0 + tx];
    __syncthreads();
    wt[(h0 + ty) * E_NUM + tx] = tile[ty][tx];
}

// ---------------- Fused gate: logits + top-4 + softmax ----------------
// grid T/64 = 256 blocks (1/CU). Block = 256 thr: lane = token, wave = h-quarter.
// Thread: acc[32] over its 720 h-elems. Double-buffered DMA, R2/R3-proven
// barrier shape (prologue; loop { barrier; DMA(s+1)->other buf; compute(s) }).
// Weight address is built ONLY from uniform values (s, wq, j) -> scalar
// s_load_dwordx16 path (R5's tid-derived component broke this: SGPR 112->32).
__global__ __launch_bounds__(256) void gate_fused(
    const float* __restrict__ x, const float* __restrict__ wt,
    const float* __restrict__ bias, float* __restrict__ out, int T) {
    __shared__ float smem[2 * SBUF];  // 75.8 KB; epilogue reuses buf0 region
    const int tid = threadIdx.x;
    const int lane = tid & 63;                                    // token in block
    const int wq = __builtin_amdgcn_readfirstlane(tid >> 6);      // wave = quarter
    const int t0 = blockIdx.x * TT;

    // DMA: wave wq stages tokens [wq*16, wq*16+16); lanes 0..35 carry the row.
    const float* gbase = x + (size_t)(t0 + wq * 16) * H_DIM + lane * 4;
    const bool act = (lane < 36);

    float acc[E_NUM];
#pragma unroll
    for (int e = 0; e < E_NUM; ++e) acc[e] = 0.f;

    // prologue: stage 0 -> buf0
#pragma unroll
    for (int i = 0; i < 16; ++i)
        if (act) GLD16(gbase + (size_t)i * H_DIM, &smem[(wq * 16 + i) * LROW + lane * 4]);

    for (int s = 0; s < NSTG; ++s) {
        __syncthreads();  // drains own DMA (vmcnt0): buf[s&1] ready; buf[(s+1)&1]'s
                          // last readers (stage s-1) are all past this barrier.
        if (s + 1 < NSTG) {
            const float* gs = gbase + (size_t)(s + 1) * SW;
            float* lb = &smem[((s + 1) & 1) * SBUF];
#pragma unroll
            for (int i = 0; i < 16; ++i)
                if (act) GLD16(gs + (size_t)i * H_DIM, &lb[(wq * 16 + i) * LROW + lane * 4]);
        }

        const float* xrow = &smem[(s & 1) * SBUF + lane * LROW + wq * 36];
        const int kb = s * SW + wq * 36;  // uniform
#pragma unroll
        for (int j = 0; j < 9; ++j) {
            float4 xv = *(const float4*)&xrow[j * 4];
#pragma unroll
            for (int c = 0; c < 4; ++c) {
                float xk = (&xv.x)[c];
                const int kg = kb + j * 4 + c;  // fully uniform -> s_load_dwordx16
                vf16 w0 = *(const vf16*)(wt + (size_t)kg * E_NUM);
                vf16 w1 = *(const vf16*)(wt + (size_t)kg * E_NUM + 16);
#pragma unroll
                for (int e = 0; e < 16; ++e) {
                    acc[e]      += xk * w0[e];
                    acc[16 + e] += xk * w1[e];
                }
            }
        }
    }

    // ---- epilogue: 4-way cross-wave reduce in LDS (reuse buf0 region;
    // stage 19 compute reads buf1 only -> disjoint), then top-4 + softmax.
    float* red = smem;  // [4][64][36]
#pragma unroll
    for (int j = 0; j < 8; ++j)
        *(float4*)&red[wq * 2304 + lane * 36 + j * 4] =
            make_float4(acc[j * 4], acc[j * 4 + 1], acc[j * 4 + 2], acc[j * 4 + 3]);
    __syncthreads();

    if (wq == 0) {
        const int t = t0 + lane;
        float logit[E_NUM];
        const float4* b4 = (const float4*)bias;
#pragma unroll
        for (int j = 0; j < 8; ++j) {
            float4 b = b4[j];
            logit[j * 4] = b.x; logit[j * 4 + 1] = b.y;
            logit[j * 4 + 2] = b.z; logit[j * 4 + 3] = b.w;
        }
#pragma unroll
        for (int g = 0; g < 4; ++g)
#pragma unroll
            for (int j = 0; j < 8; ++j) {
                float4 v = *(const float4*)&red[g * 2304 + lane * 36 + j * 4];
                logit[j * 4] += v.x; logit[j * 4 + 1] += v.y;
                logit[j * 4 + 2] += v.z; logit[j * 4 + 3] += v.w;
            }

        // top-4 descending, ties -> lowest index (strict >, ascending scan)
        int idx[TOPK];
        float val[TOPK];
#pragma unroll
        for (int k = 0; k < TOPK; ++k) {
            float best = -INFINITY;
            int bi = 0;
#pragma unroll
            for (int e = 0; e < E_NUM; ++e) {
                bool taken = false;
                for (int p = 0; p < k; ++p) taken = taken || (idx[p] == e);
                float v = logit[e];
                if (!taken && v > best) { best = v; bi = e; }
            }
            idx[k] = bi;
            val[k] = best;
        }
        float ex[TOPK], sum = 0.f;
#pragma unroll
        for (int k = 0; k < TOPK; ++k) { ex[k] = expf(val[k] - val[0]); sum += ex[k]; }
        float inv = 1.f / sum;
#pragma unroll
        for (int k = 0; k < TOPK; ++k) {
            out[(size_t)t * 4 + k] = (float)idx[k];                 // indices (coalesced 1KB)
            out[(size_t)T * 4 + (size_t)t * 4 + k] = ex[k] * inv;   // weights
        }
    }
}

extern "C" void kernel_launch(void* const* d_in, const int* in_sizes, int n_in,
                              void* d_out, int out_size, void* d_ws, size_t ws_size,
                              hipStream_t stream) {
    const float* x    = (const float*)d_in[0];  // [B,S,H] fp32
    const float* w    = (const float*)d_in[1];  // [E,H] fp32
    const float* bias = (const float*)d_in[2];  // [E] fp32
    float* out = (float*)d_out;

    const int T = in_sizes[0] / H_DIM;  // 16384

    float* wt = (float*)d_ws;  // [H][E] = 368 KB

    transpose_w<<<dim3(H_DIM / 32), dim3(32, 32), 0, stream>>>(w, wt);
    gate_fused<<<dim3(T / TT), 256, 0, stream>>>(x, wt, bias, out, T);
}

// Round 7
// 285.834 us; speedup vs baseline: 1.4871x; 1.3504x over previous
//
#include <hip/hip_runtime.h>
#include <math.h>

#define H_DIM 2880
#define E_NUM 32
#define TOPK 4
#define TT 64        // tokens per block
#define KW 96        // k-window per stage
#define NSTG 30      // H_DIM / KW
#define GRP 772      // LDS group: 8 rows x 96 dw + 4 dw pad (bank-stagger)
#define XB 0         // x buffers at XB + p*XBS
#define XBS 6176     // 8 groups x 772
#define WB 12352     // w buffers at WB + p*WBS
#define WBS 3088     // 4 groups x 772
#define REDR 36      // reduce row stride (32 padded to 36)
#define LGTO 18432   // logits area (after red[8][64][36])
#define SMSZ 20736

// async global->LDS DMA, 16B/lane; dest = wave-uniform base + lane*16.
#define GLD16(gp, lp)                                                  \
    __builtin_amdgcn_global_load_lds(                                  \
        (const __attribute__((address_space(1))) void*)(gp),           \
        (__attribute__((address_space(3))) void*)(lp), 16, 0, 0)

// Single fused kernel. Grid 256 (1 block/CU), block 512 (8 waves, 2/SIMD).
// Per lane: 8tok x 8exp register tile, acc[64]. lane = (kg<<5)|(eg<<3)|tg.
// Wave wq owns k-slice [wq*12, wq*12+12) of each 96-k window; kg-halves split
// it 6/6 (kg0: k0-3 + k8-9, kg1: k4-7 + k10-11 -- keeps b128 16-B alignment).
// NO scalar memory in the K-loop: x and w both come from LDS via DMA staging
// (R2/R3/R6-proven shape) -> ds_read chains pipeline with lgkmcnt(N), unlike
// SMEM whose out-of-order returns force lgkmcnt(0) full drains (R2/R3/R6's
// invariant ~10-18% VALUBusy).
__global__ __launch_bounds__(512, 2) void gate_fused(
    const float* __restrict__ x, const float* __restrict__ w,
    const float* __restrict__ bias, float* __restrict__ out, int T) {
    __shared__ float sm[SMSZ];
    const int tid = threadIdx.x;
    const int lane = tid & 63;
    const int wq = __builtin_amdgcn_readfirstlane(tid >> 6);
    const int tg = lane & 7;            // token group: tokens 8tg..8tg+7
    const int eg = (lane >> 3) & 3;     // expert group: experts 8eg..8eg+7
    const int kg = lane >> 5;           // k-half within wave slice
    const int t0 = blockIdx.x * TT;

    // DMA precompute: wave wq stages x-group wq (tokens 8wq..+8); waves 0-3
    // also stage w-group wq (experts 8wq..+8). 3 instrs each (768 dw/group).
    const float* gx[3]; const float* gw[3]; int lx[3], lw[3];
#pragma unroll
    for (int i = 0; i < 3; ++i) {
        const int d = i * 256 + lane * 4;       // dw within group, lane-contiguous
        const int r = d / KW, kk = d % KW;      // row, k-offset (16B chunk never straddles)
        gx[i] = x + (size_t)(t0 + wq * 8 + r) * H_DIM + kk;
        lx[i] = XB + wq * GRP + d;
        gw[i] = w + (size_t)((wq & 3) * 8 + r) * H_DIM + kk;  // clamp: only wq<4 issues
        lw[i] = WB + (wq & 3) * GRP + d;
    }

    float acc[64];
#pragma unroll
    for (int i = 0; i < 64; ++i) acc[i] = 0.f;

    // prologue: stage 0 -> p=0 buffers
#pragma unroll
    for (int i = 0; i < 3; ++i) GLD16(gx[i], &sm[lx[i]]);
    if (wq < 4) {
#pragma unroll
        for (int i = 0; i < 3; ++i) GLD16(gw[i], &sm[lw[i]]);
    }

    const int koA = wq * 12 + kg * 4;      // unit A: 4k, b128 (16-B aligned)
    const int koB = wq * 12 + 8 + kg * 2;  // unit B: 2k, b64  (8-B aligned)

    for (int s = 0; s < NSTG; ++s) {
        __syncthreads();  // drains own DMA (vmcnt0): buf[s&1] ready; stage s-1's
                          // readers of buf[(s+1)&1] are all past this barrier.
        if (s + 1 < NSTG) {
            const size_t go = (size_t)(s + 1) * KW;
            const int pb = (s + 1) & 1;
#pragma unroll
            for (int i = 0; i < 3; ++i) GLD16(gx[i] + go, &sm[lx[i] + pb * XBS]);
            if (wq < 4) {
#pragma unroll
                for (int i = 0; i < 3; ++i) GLD16(gw[i] + go, &sm[lw[i] + pb * WBS]);
            }
        }
        const int p = s & 1;
        const float* xbp = &sm[XB + p * XBS + tg * GRP];
        const float* wbp = &sm[WB + p * WBS + eg * GRP];

        float4 xa[8], wa[8];
#pragma unroll
        for (int i = 0; i < 8; ++i) xa[i] = *(const float4*)(xbp + i * KW + koA);
#pragma unroll
        for (int j = 0; j < 8; ++j) wa[j] = *(const float4*)(wbp + j * KW + koA);
#pragma unroll
        for (int i = 0; i < 8; ++i)
#pragma unroll
            for (int j = 0; j < 8; ++j)
                acc[i * 8 + j] += xa[i].x * wa[j].x + xa[i].y * wa[j].y +
                                  xa[i].z * wa[j].z + xa[i].w * wa[j].w;

        float2 x2[8], w2[8];
#pragma unroll
        for (int i = 0; i < 8; ++i) x2[i] = *(const float2*)(xbp + i * KW + koB);
#pragma unroll
        for (int j = 0; j < 8; ++j) w2[j] = *(const float2*)(wbp + j * KW + koB);
#pragma unroll
        for (int i = 0; i < 8; ++i)
#pragma unroll
            for (int j = 0; j < 8; ++j)
                acc[i * 8 + j] += x2[i].x * w2[j].x + x2[i].y * w2[j].y;
    }

    __syncthreads();  // all compute + DMA done; LDS safe to repurpose

    // fold the kg halves: lanes l and l^32 share (tg,eg), disjoint k-subsets
#pragma unroll
    for (int d = 0; d < 64; ++d) acc[d] += __shfl_xor(acc[d], 32, 64);

    // lanes 0-31 park wave partials: red[wq][tok][e] (stride 36)
    if (kg == 0) {
#pragma unroll
        for (int i = 0; i < 8; ++i) {
            float* rp = &sm[wq * 2304 + (tg * 8 + i) * REDR + eg * 8];
            *(float4*)(rp + 0) = make_float4(acc[i * 8 + 0], acc[i * 8 + 1],
                                             acc[i * 8 + 2], acc[i * 8 + 3]);
            *(float4*)(rp + 4) = make_float4(acc[i * 8 + 4], acc[i * 8 + 5],
                                             acc[i * 8 + 6], acc[i * 8 + 7]);
        }
    }
    __syncthreads();

    // sum the 8 wave partials + bias: thread -> 4 outputs (tok = tid>>3, e4)
    {
        const int tok = tid >> 3, e4 = (tid & 7) * 4;
        float4 sg = *(const float4*)(bias + e4);
#pragma unroll
        for (int q = 0; q < 8; ++q) {
            float4 v = *(const float4*)&sm[q * 2304 + tok * REDR + e4];
            sg.x += v.x; sg.y += v.y; sg.z += v.z; sg.w += v.w;
        }
        *(float4*)&sm[LGTO + tok * REDR + e4] = sg;
    }
    __syncthreads();

    // wave 0: per-token top-4 + softmax + store
    if (tid < 64) {
        const int t = t0 + tid;
        float logit[E_NUM];
#pragma unroll
        for (int j = 0; j < 8; ++j) {
            float4 v = *(const float4*)&sm[LGTO + tid * REDR + j * 4];
            logit[j * 4] = v.x; logit[j * 4 + 1] = v.y;
            logit[j * 4 + 2] = v.z; logit[j * 4 + 3] = v.w;
        }

        // top-4 descending, ties -> lowest index (strict >, ascending scan)
        int idx[TOPK];
        float val[TOPK];
#pragma unroll
        for (int k = 0; k < TOPK; ++k) {
            float best = -INFINITY;
            int bi = 0;
#pragma unroll
            for (int e = 0; e < E_NUM; ++e) {
                bool taken = false;
                for (int p = 0; p < k; ++p) taken = taken || (idx[p] == e);
                float v = logit[e];
                if (!taken && v > best) { best = v; bi = e; }
            }
            idx[k] = bi;
            val[k] = best;
        }
        float ex[TOPK], ssum = 0.f;
#pragma unroll
        for (int k = 0; k < TOPK; ++k) { ex[k] = expf(val[k] - val[0]); ssum += ex[k]; }
        const float inv = 1.f / ssum;

        *(float4*)(out + (size_t)t * 4) =
            make_float4((float)idx[0], (float)idx[1], (float)idx[2], (float)idx[3]);
        *(float4*)(out + (size_t)T * 4 + (size_t)t * 4) =
            make_float4(ex[0] * inv, ex[1] * inv, ex[2] * inv, ex[3] * inv);
    }
}

extern "C" void kernel_launch(void* const* d_in, const int* in_sizes, int n_in,
                              void* d_out, int out_size, void* d_ws, size_t ws_size,
                              hipStream_t stream) {
    const float* x    = (const float*)d_in[0];  // [B,S,H] fp32
    const float* w    = (const float*)d_in[1];  // [E,H] fp32
    const float* bias = (const float*)d_in[2];  // [E] fp32
    float* out = (float*)d_out;

    const int T = in_sizes[0] / H_DIM;  // 16384

    gate_fused<<<dim3(T / TT), 512, 0, stream>>>(x, w, bias, out, T);
}

// Round 8
// 275.888 us; speedup vs baseline: 1.5408x; 1.0361x over previous
//
#include <hip/hip_runtime.h>
#include <math.h>

#define H_DIM 2880
#define E_NUM 32
#define TOPK 4
#define TT 32        // tokens per block
#define KW 96        // k-window per stage
#define NSTG 30      // H_DIM / KW
#define GRP 772      // LDS group: 8 rows x 96 dw + 4 dw pad (bank stagger: 772%32=4)
#define XB 0         // x buffers: XB + p*XBS
#define XBS 3088     // 4 groups x 772
#define WB 6176      // w buffers: WB + p*WBS
#define WBS 3088
#define SMSZ 12352   // 49.4 KB -> 2 blocks/CU
#define REDR 36
#define LGTO 4608    // logits area (after red[4][32][36]); inside p0 regions only

// async global->LDS DMA, 16B/lane; dest = wave-uniform base + lane*16.
#define GLD16(gp, lp)                                                  \
    __builtin_amdgcn_global_load_lds(                                  \
        (const __attribute__((address_space(1))) void*)(gp),           \
        (__attribute__((address_space(3))) void*)(lp), 16, 0, 0)

// Grid 512 (2 blocks/CU — R7 was 1/CU and convoyed at every stage barrier),
// block 256 = 4 waves. Per lane: 8tok x 8exp tile, acc[64]; 16-way k-split:
// ks = wq*4 + ksl, lane = ksl*16 + et*4 + tt. Slice of KW=96: dw {ks*4+u,u<4}
// (b128, 16B-aligned) + {64+ks*2,+1} (b64, 8B-aligned). No scalar-mem in loop.
// Every wave issues identical DMA work each stage (3 x-instr + 3 w-instr).
__global__ __launch_bounds__(256, 2) void gate_fused(
    const float* __restrict__ x, const float* __restrict__ w,
    const float* __restrict__ bias, float* __restrict__ out, int T) {
    __shared__ float sm[SMSZ];
    const int tid = threadIdx.x;
    const int lane = tid & 63;
    const int wq = __builtin_amdgcn_readfirstlane(tid >> 6);
    const int tt = lane & 3;            // token group (8 tokens)
    const int et = (lane >> 2) & 3;     // expert group (8 experts)
    const int ksl = lane >> 4;          // intra-wave k-slice
    const int t0 = blockIdx.x * TT;

    // DMA: wave wq stages x-group wq (tokens 8wq..+8) and w-group wq (experts
    // 8wq..+8); 3 instrs each, 768 dw/group, lane-contiguous 16-B chunks.
    const float* gx[3]; const float* gw[3]; int lx[3], lw[3];
#pragma unroll
    for (int i = 0; i < 3; ++i) {
        const int d = i * 256 + lane * 4;   // dw within group
        const int r = d / KW, kk = d % KW;  // row, k-offset (no 16B straddle: 96%4==0)
        gx[i] = x + (size_t)(t0 + wq * 8 + r) * H_DIM + kk;
        gw[i] = w + (size_t)(wq * 8 + r) * H_DIM + kk;
        lx[i] = XB + wq * GRP + d;
        lw[i] = WB + wq * GRP + d;
    }

    float acc[64];
#pragma unroll
    for (int i = 0; i < 64; ++i) acc[i] = 0.f;

    // prologue: stage 0 -> p=0 buffers
#pragma unroll
    for (int i = 0; i < 3; ++i) GLD16(gx[i], &sm[lx[i]]);
#pragma unroll
    for (int i = 0; i < 3; ++i) GLD16(gw[i], &sm[lw[i]]);

    const int ks = wq * 4 + ksl;
    const int koA = ks * 4;        // b128 unit, 16-B aligned
    const int koB = 64 + ks * 2;   // b64 unit, 8-B aligned

    for (int s = 0; s < NSTG; ++s) {
        __syncthreads();  // drains own DMA (vmcnt0): buf[s&1] ready; stage s-1's
                          // readers of buf[(s+1)&1] are all past this barrier.
        if (s + 1 < NSTG) {
            const size_t go = (size_t)(s + 1) * KW;
            const int pb = (s + 1) & 1;
#pragma unroll
            for (int i = 0; i < 3; ++i) GLD16(gx[i] + go, &sm[lx[i] + pb * XBS]);
#pragma unroll
            for (int i = 0; i < 3; ++i) GLD16(gw[i] + go, &sm[lw[i] + pb * WBS]);
        }
        const int p = s & 1;
        const float* xbp = &sm[XB + p * XBS + tt * GRP];
        const float* wbp = &sm[WB + p * WBS + et * GRP];

        float4 xa[8], wa[8];
#pragma unroll
        for (int i = 0; i < 8; ++i) xa[i] = *(const float4*)(xbp + i * KW + koA);
#pragma unroll
        for (int j = 0; j < 8; ++j) wa[j] = *(const float4*)(wbp + j * KW + koA);
#pragma unroll
        for (int i = 0; i < 8; ++i)
#pragma unroll
            for (int j = 0; j < 8; ++j)
                acc[i * 8 + j] += xa[i].x * wa[j].x + xa[i].y * wa[j].y +
                                  xa[i].z * wa[j].z + xa[i].w * wa[j].w;

        float2 x2[8], w2[8];
#pragma unroll
        for (int i = 0; i < 8; ++i) x2[i] = *(const float2*)(xbp + i * KW + koB);
#pragma unroll
        for (int j = 0; j < 8; ++j) w2[j] = *(const float2*)(wbp + j * KW + koB);
#pragma unroll
        for (int i = 0; i < 8; ++i)
#pragma unroll
            for (int j = 0; j < 8; ++j)
                acc[i * 8 + j] += x2[i].x * w2[j].x + x2[i].y * w2[j].y;
    }

    __syncthreads();  // all compute + DMA done; LDS safe to repurpose

    // fold intra-wave k-slices: lanes l, l^16, l^32, l^48 share (tt,et)
#pragma unroll
    for (int d = 0; d < 64; ++d) {
        acc[d] += __shfl_xor(acc[d], 16, 64);
        acc[d] += __shfl_xor(acc[d], 32, 64);
    }

    // lanes 0-15 (ksl==0) park wave partial: red[wq][tok][e] (stride 36)
    if (ksl == 0) {
#pragma unroll
        for (int i = 0; i < 8; ++i) {
            float* rp = &sm[wq * (TT * REDR) + (tt * 8 + i) * REDR + et * 8];
            *(float4*)(rp + 0) = make_float4(acc[i * 8 + 0], acc[i * 8 + 1],
                                             acc[i * 8 + 2], acc[i * 8 + 3]);
            *(float4*)(rp + 4) = make_float4(acc[i * 8 + 4], acc[i * 8 + 5],
                                             acc[i * 8 + 6], acc[i * 8 + 7]);
        }
    }
    __syncthreads();

    // sum 4 wave partials + bias: thread -> 4 logits (tok = tid>>3, e4)
    {
        const int tok = tid >> 3, e4 = (tid & 7) * 4;
        float4 sg = *(const float4*)(bias + e4);
#pragma unroll
        for (int q = 0; q < 4; ++q) {
            float4 v = *(const float4*)&sm[q * (TT * REDR) + tok * REDR + e4];
            sg.x += v.x; sg.y += v.y; sg.z += v.z; sg.w += v.w;
        }
        *(float4*)&sm[LGTO + tok * REDR + e4] = sg;
    }
    __syncthreads();

    // first 32 lanes: per-token top-4 + softmax + store
    if (tid < TT) {
        const int t = t0 + tid;
        float logit[E_NUM];
#pragma unroll
        for (int j = 0; j < 8; ++j) {
            float4 v = *(const float4*)&sm[LGTO + tid * REDR + j * 4];
            logit[j * 4] = v.x; logit[j * 4 + 1] = v.y;
            logit[j * 4 + 2] = v.z; logit[j * 4 + 3] = v.w;
        }

        // top-4 descending, ties -> lowest index (strict >, ascending scan)
        int idx[TOPK];
        float val[TOPK];
#pragma unroll
        for (int k = 0; k < TOPK; ++k) {
            float best = -INFINITY;
            int bi = 0;
#pragma unroll
            for (int e = 0; e < E_NUM; ++e) {
                bool taken = false;
                for (int p = 0; p < k; ++p) taken = taken || (idx[p] == e);
                float v = logit[e];
                if (!taken && v > best) { best = v; bi = e; }
            }
            idx[k] = bi;
            val[k] = best;
        }
        float ex[TOPK], ssum = 0.f;
#pragma unroll
        for (int k = 0; k < TOPK; ++k) { ex[k] = expf(val[k] - val[0]); ssum += ex[k]; }
        const float inv = 1.f / ssum;

        *(float4*)(out + (size_t)t * 4) =
            make_float4((float)idx[0], (float)idx[1], (float)idx[2], (float)idx[3]);
        *(float4*)(out + (size_t)T * 4 + (size_t)t * 4) =
            make_float4(ex[0] * inv, ex[1] * inv, ex[2] * inv, ex[3] * inv);
    }
}

extern "C" void kernel_launch(void* const* d_in, const int* in_sizes, int n_in,
                              void* d_out, int out_size, void* d_ws, size_t ws_size,
                              hipStream_t stream) {
    const float* x    = (const float*)d_in[0];  // [B,S,H] fp32
    const float* w    = (const float*)d_in[1];  // [E,H] fp32
    const float* bias = (const float*)d_in[2];  // [E] fp32
    float* out = (float*)d_out;

    const int T = in_sizes[0] / H_DIM;  // 16384

    gate_fused<<<dim3(T / TT), 256, 0, stream>>>(x, w, bias, out, T);
}